// Round 12
// baseline (519.405 us; speedup 1.0000x reference)
//
#include <hip/hip_runtime.h>

namespace {
constexpr int NZ = 256, NX = 256, NT = 256, NR = 128, B = 4;
constexpr int K = 16;                    // fused time steps per launch
constexpr int OROWS = 4;                 // rows owned (written back) per block
constexpr int IROWS = OROWS + 2 * K;     // 36-row window (K-step cone)
constexpr int NSTRIP = 4;                // z-strips per block
constexpr int RPT = IROWS / NSTRIP;      // 9 rows per thread
constexpr int ZB = NZ / OROWS;           // 64 z-blocks per shot
constexpr int NBLK = B * ZB;             // 256 blocks
constexpr int NL = NT / K;               // 16 launches
constexpr int NXCD = 8;
constexpr int CHUNK = NBLK / NXCD;       // 32 logical blocks per XCD
constexpr float DT = 1e-3f, DH = 10.0f, OMEGA = 10.0f;
constexpr float TS  = 1.0f / OMEGA;
constexpr float CBv = 1.0f + DT / (2.0f * TS);
constexpr float CA  = (1.0f - DT / (2.0f * TS)) / CBv;

// lane i <- lane i-1 (wave_shr:1); lane 0 <- 0
__device__ inline float dpp_shr1(float v) {
  int r = __builtin_amdgcn_update_dpp(0, __builtin_bit_cast(int, v),
                                      0x138, 0xF, 0xF, false);
  return __builtin_bit_cast(float, r);
}
// lane i <- lane i+1 (wave_shl:1); lane 63 <- 0
__device__ inline float dpp_shl1(float v) {
  int r = __builtin_amdgcn_update_dpp(0, __builtin_bit_cast(int, v),
                                      0x130, 0xF, 0xF, false);
  return __builtin_bit_cast(float, r);
}
}

// cf = (a1, b2, b3, 0)
__global__ void coef_kernel(const float* __restrict__ vp, const float* __restrict__ rho,
                            const float* __restrict__ Q, float4* __restrict__ cf) {
  int i = blockIdx.x * blockDim.x + threadIdx.x;
  if (i >= NZ * NX) return;
  float v = vp[i], rh = rho[i], q = Q[i];
  float kappa = rh * v * v, tau = 1.0f / q;
  cf[i] = make_float4(DT / (rh * DH), DT * kappa * tau / (TS * CBv * DH),
                      DT * kappa * (1.0f + tau) / DH, 0.0f);
}

// Time-skewed K=16 block; identical to the verified round-11 kernel EXCEPT
// the cross-wave edge values (p[x-1] for lane 0, vx[x+1] for lane 63) are
// read inline from LDS per row instead of being staged in RPT-deep register
// arrays. Those two arrays (18 VGPRs, live across the unrolled 9-row loop)
// pushed the kernel against the 128-VGPR cap -> scratch spills in the hot
// loop. Inline 1-lane ds_reads carry the same data with zero long-lived regs.
__global__ __launch_bounds__(1024, 4) void step_fused(
    const float4* __restrict__ Sin, float4* __restrict__ Sout,
    const float4* __restrict__ Cf, const float* __restrict__ wav,
    const int* __restrict__ src_z, const int* __restrict__ src_x,
    const int* __restrict__ rec_x, const int* __restrict__ rec_z,
    float* __restrict__ out, int t0)
{
  const int tid  = threadIdx.x;
  const int x    = tid & (NX - 1);       // column 0..255
  const int g    = tid >> 8;             // strip 0..3
  const int lane = x & 63;               // lane in wave
  const int wx   = x >> 6;               // wave-in-strip 0..3
  const int j0   = g * RPT;              // first window row of strip
  const int lbid = (blockIdx.x & (NXCD - 1)) * CHUNK + (blockIdx.x >> 3);
  const int b    = lbid / ZB, zb = lbid % ZB;
  const int z0   = zb * OROWS;
  const int zi0  = z0 - K;               // first loaded global row (may be <0)
  const size_t base = (size_t)b * NZ * NX;

  __shared__ float pse[NSTRIP][NX];      // strip bottom-row p  (row j0+RPT-1)
  __shared__ float vze[NSTRIP][NX];      // strip top-row vz    (row j0)
  __shared__ float pxe[NSTRIP][4][RPT];  // lane-63 p  of each wave
  __shared__ float vxe_s[NSTRIP][4][RPT];// lane-0  vx of each wave
  __shared__ float prow[NX];             // receiver row staging
  __shared__ float wav_s[K];
  __shared__ int   rx_s[NR];

  float pr[RPT], vxr[RPT], vz[RPT], rr[RPT], a1[RPT], b2[RPT], b3[RPT];

  // ---- load window (AoS float4); zero coefs outside domain = exact ghosts ----
  #pragma unroll
  for (int jj = 0; jj < RPT; ++jj) {
    int gz = zi0 + j0 + jj;
    bool in = (unsigned)gz < (unsigned)NZ;
    float4 st = in ? Sin[base + (size_t)gz * NX + x] : make_float4(0, 0, 0, 0);
    float4 cf = in ? Cf[(size_t)gz * NX + x]        : make_float4(0, 0, 0, 0);
    pr[jj] = st.x; vxr[jj] = st.y; vz[jj] = st.z; rr[jj] = st.w;
    a1[jj] = cf.x; b2[jj] = cf.y; b3[jj] = cf.z;
  }
  pse[g][x] = pr[RPT - 1];
  if (wx < 3 && lane == 63) {
    #pragma unroll
    for (int jj = 0; jj < RPT; ++jj) pxe[g][wx][jj] = pr[jj];
  }
  if (tid < NR) rx_s[tid] = rec_x[tid];
  if (tid < K)  wav_s[tid] = wav[b * NT + t0 + tid];
  const int sz = src_z[b], sx = src_x[b];
  const int rz = rec_z[0];
  const bool owner = (rz >= z0 && rz < z0 + OROWS);  // unique block per shot
  const int jrow = rz - zi0;                         // in [K, K+OROWS)
  __syncthreads();

  for (int s = 0; s < K; ++s) {
    // ---------- phase A: velocities ----------
    float pu0 = (g > 0) ? pse[g - 1][x] : 0.0f;      // row j0-1 p (old)
    #pragma unroll
    for (int jj = 0; jj < RPT; ++jj) {
      float pc = pr[jj];
      float pl = dpp_shr1(pc);                       // p[x-1] in-wave
      if (lane == 0)                                 // wave seam / x==0 ghost
        pl = (wx > 0) ? pxe[g][wx - 1][jj] : 0.0f;
      float pu = jj ? pr[jj - 1] : pu0;              // p[j-1]
      vxr[jj] -= a1[jj] * (pc - pl);
      vz[jj]  -= a1[jj] * (pc - pu);
    }
    vze[g][x] = vz[0];                               // strip top vz for strip g-1
    if (wx > 0 && lane == 0) {                       // cross-wave vx[x+1] source
      #pragma unroll
      for (int jj = 0; jj < RPT; ++jj) vxe_s[g][wx][jj] = vxr[jj];
    }
    __syncthreads();

    // ---------- phase B: div, memory var, pressure ----------
    float vzb_ = (g < NSTRIP - 1) ? vze[g + 1][x] : 0.0f;  // row j0+RPT vz
    const float xi = wav_s[s];
    #pragma unroll
    for (int jj = 0; jj < RPT; ++jj) {
      float vxR = dpp_shl1(vxr[jj]);                 // vx[x+1] in-wave
      if (lane == 63)                                // wave seam / x==255 ghost
        vxR = (wx < 3) ? vxe_s[g][wx + 1][jj] : 0.0f;
      float vzn = (jj < RPT - 1) ? vz[jj + 1] : vzb_;
      float div = (vxR - vxr[jj]) + (vzn - vz[jj]);
      float rn = CA * rr[jj] - b2[jj] * div;
      rr[jj] = rn;
      float pn = pr[jj] - b3[jj] * div + DT * rn;
      if (zi0 + j0 + jj == sz && x == sx) pn += xi;  // source injection
      pr[jj] = pn;
    }
    pse[g][x] = pr[RPT - 1];
    if (wx < 3 && lane == 63) {
      #pragma unroll
      for (int jj = 0; jj < RPT; ++jj) pxe[g][wx][jj] = pr[jj];
    }
    if (owner) {                                     // stage receiver row
      #pragma unroll
      for (int jj = 0; jj < RPT; ++jj)
        if (j0 + jj == jrow) prow[x] = pr[jj];
    }
    __syncthreads();
    // probe reads complete before any thread reaches next A->B barrier -> safe
    if (owner && tid < NR)
      out[(size_t)(t0 + s) * NR * B + (size_t)tid * B + b] = prow[rx_s[tid]];
  }

  // ---- store owned rows (valid after exactly K steps) ----
  #pragma unroll
  for (int jj = 0; jj < RPT; ++jj) {
    int j = j0 + jj;
    if (j >= K && j < K + OROWS)
      Sout[base + (size_t)(zi0 + j) * NX + x] =
          make_float4(pr[jj], vxr[jj], vz[jj], rr[jj]);
  }
}

extern "C" void kernel_launch(void* const* d_in, const int* in_sizes, int n_in,
                              void* d_out, int out_size, void* d_ws, size_t ws_size,
                              hipStream_t stream) {
  const float* xw  = (const float*)d_in[0];
  const float* vp  = (const float*)d_in[1];
  const float* rho = (const float*)d_in[2];
  const float* Q   = (const float*)d_in[3];
  const int* src_z = (const int*)d_in[4];
  const int* src_x = (const int*)d_in[5];
  const int* rec_x = (const int*)d_in[6];
  const int* rec_z = (const int*)d_in[7];
  float* out = (float*)d_out;

  const size_t S = (size_t)B * NZ * NX;          // cells per state buffer
  float4* s0 = (float4*)d_ws;                    // state ping  [S] float4
  float4* s1 = s0 + S;                           // state pong  [S] float4
  float4* cf = s1 + S;                           // coefs       [NZ*NX] float4

  hipMemsetAsync(s0, 0, S * sizeof(float4), stream);   // zero initial state
  coef_kernel<<<(NZ * NX + 255) / 256, 256, 0, stream>>>(vp, rho, Q, cf);

  for (int l = 0; l < NL; ++l) {
    float4* in   = (l & 1) ? s1 : s0;
    float4* out4 = (l & 1) ? s0 : s1;
    step_fused<<<NBLK, 1024, 0, stream>>>(in, out4, cf, xw, src_z, src_x,
                                          rec_x, rec_z, out, l * K);
  }
}

// Round 14
// 372.708 us; speedup vs baseline: 1.3936x; 1.3936x over previous
//
#include <hip/hip_runtime.h>

namespace {
constexpr int NZ = 256, NX = 256, NT = 256, NR = 128, B = 4;
constexpr int K = 8;                     // fused time steps per launch
constexpr int OROWS = 4;                 // rows owned (written back) per block
constexpr int IROWS = OROWS + 2 * K;     // 20-row window (K-step cone)
constexpr int NSTRIP = 4;                // z-strips per block
constexpr int RPT = IROWS / NSTRIP;      // 5 rows per thread
constexpr int ZB = NZ / OROWS;           // 64 z-blocks per shot
constexpr int NBLK = B * ZB;             // 256 blocks
constexpr int NL = NT / K;               // 32 launches
constexpr int NXCD = 8;
constexpr int CHUNK = NBLK / NXCD;       // 32 logical blocks per XCD
constexpr float DT = 1e-3f, DH = 10.0f, OMEGA = 10.0f;
constexpr float TS  = 1.0f / OMEGA;
constexpr float CBv = 1.0f + DT / (2.0f * TS);
constexpr float CA  = (1.0f - DT / (2.0f * TS)) / CBv;

// lane i <- lane i-1 (wave_shr:1); lane 0 <- 0
__device__ inline float dpp_shr1(float v) {
  int r = __builtin_amdgcn_update_dpp(0, __builtin_bit_cast(int, v),
                                      0x138, 0xF, 0xF, false);
  return __builtin_bit_cast(float, r);
}
// lane i <- lane i+1 (wave_shl:1); lane 63 <- 0
__device__ inline float dpp_shl1(float v) {
  int r = __builtin_amdgcn_update_dpp(0, __builtin_bit_cast(int, v),
                                      0x130, 0xF, 0xF, false);
  return __builtin_bit_cast(float, r);
}
}

// cf = (a1, b2, b3, 0) = (DT/(rho DH), DT k tau/(TS cb DH), DT k (1+tau)/DH, 0)
__global__ void coef_kernel(const float* __restrict__ vp, const float* __restrict__ rho,
                            const float* __restrict__ Q, float4* __restrict__ cf) {
  int i = blockIdx.x * blockDim.x + threadIdx.x;
  if (i >= NZ * NX) return;
  float v = vp[i], rh = rho[i], q = Q[i];
  float kappa = rh * v * v, tau = 1.0f / q;
  cf[i] = make_float4(DT / (rh * DH), DT * kappa * tau / (TS * CBv * DH),
                      DT * kappa * (1.0f + tau) / DH, 0.0f);
}

// Time-skewed K-step block (verified round-8 kernel, 370 us). 1024 threads =
// 4 z-strips x 256 cols; thread holds 5 rows of (p,vx,vz,r,a1,b2,b3) in
// registers. x-neighbors via DPP wave shifts; strip seams via small LDS
// buffers. XCD-chunked logical-block swizzle keeps each block's window rows
// (written last launch by z-neighbors) and coefficient rows resident in its
// own XCD's L2.
__global__ __launch_bounds__(1024, 4) void step_fused(
    const float4* __restrict__ Sin, float4* __restrict__ Sout,
    const float4* __restrict__ Cf, const float* __restrict__ wav,
    const int* __restrict__ src_z, const int* __restrict__ src_x,
    const int* __restrict__ rec_x, const int* __restrict__ rec_z,
    float* __restrict__ out, int t0)
{
  const int tid  = threadIdx.x;
  const int x    = tid & (NX - 1);       // column 0..255
  const int g    = tid >> 8;             // strip 0..3
  const int lane = x & 63;               // lane in wave
  const int wx   = x >> 6;               // wave-in-strip 0..3
  const int j0   = g * RPT;              // first window row of strip
  const int lbid = (blockIdx.x & (NXCD - 1)) * CHUNK + (blockIdx.x >> 3);
  const int b    = lbid / ZB, zb = lbid % ZB;
  const int z0   = zb * OROWS;
  const int zi0  = z0 - K;               // first loaded global row (may be <0)
  const size_t base = (size_t)b * NZ * NX;

  __shared__ float pse[NSTRIP][NX];      // strip bottom-row p  (row j0+RPT-1)
  __shared__ float vze[NSTRIP][NX];      // strip top-row vz    (row j0)
  __shared__ float pxe[NSTRIP][4][RPT];  // lane-63 p  of each wave (5 rows)
  __shared__ float vxe_s[NSTRIP][4][RPT];// lane-0  vx of each wave (5 rows)
  __shared__ float prow[NX];             // receiver row staging
  __shared__ float wav_s[K];
  __shared__ int   rx_s[NR];

  float pr[RPT], vxr[RPT], vz[RPT], rr[RPT], a1[RPT], b2[RPT], b3[RPT];

  // ---- load window (AoS float4); zero coefs outside domain = exact ghosts ----
  #pragma unroll
  for (int jj = 0; jj < RPT; ++jj) {
    int gz = zi0 + j0 + jj;
    bool in = (unsigned)gz < (unsigned)NZ;
    float4 st = in ? Sin[base + (size_t)gz * NX + x] : make_float4(0, 0, 0, 0);
    float4 cf = in ? Cf[(size_t)gz * NX + x]        : make_float4(0, 0, 0, 0);
    pr[jj] = st.x; vxr[jj] = st.y; vz[jj] = st.z; rr[jj] = st.w;
    a1[jj] = cf.x; b2[jj] = cf.y; b3[jj] = cf.z;
  }
  pse[g][x] = pr[RPT - 1];
  if (wx < 3 && lane == 63) {
    #pragma unroll
    for (int jj = 0; jj < RPT; ++jj) pxe[g][wx][jj] = pr[jj];
  }
  if (tid < NR) rx_s[tid] = rec_x[tid];
  if (tid < K)  wav_s[tid] = wav[b * NT + t0 + tid];
  const int sz = src_z[b], sx = src_x[b];
  const int rz = rec_z[0];
  const bool owner = (rz >= z0 && rz < z0 + OROWS);  // unique block per shot
  const int jrow = rz - zi0;                         // in [K, K+OROWS)
  __syncthreads();

  for (int s = 0; s < K; ++s) {
    // ---------- phase A: velocities ----------
    float pu0 = (g > 0) ? pse[g - 1][x] : 0.0f;      // row j0-1 p (old)
    float ple[RPT] = {0, 0, 0, 0, 0};
    if (wx > 0 && lane == 0) {                       // cross-wave p[x-1]
      #pragma unroll
      for (int jj = 0; jj < RPT; ++jj) ple[jj] = pxe[g][wx - 1][jj];
    }
    #pragma unroll
    for (int jj = 0; jj < RPT; ++jj) {
      float pc = pr[jj];
      float pl = dpp_shr1(pc);                       // p[x-1] in-wave
      if (lane == 0) pl = ple[jj];                   // x==0 -> 0 ghost
      float pu = jj ? pr[jj - 1] : pu0;              // p[j-1]
      vxr[jj] -= a1[jj] * (pc - pl);
      vz[jj]  -= a1[jj] * (pc - pu);
    }
    vze[g][x] = vz[0];                               // strip top vz for strip g-1
    if (wx > 0 && lane == 0) {                       // cross-wave vx[x+1] source
      #pragma unroll
      for (int jj = 0; jj < RPT; ++jj) vxe_s[g][wx][jj] = vxr[jj];
    }
    __syncthreads();

    // ---------- phase B: div, memory var, pressure ----------
    float vzb_ = (g < NSTRIP - 1) ? vze[g + 1][x] : 0.0f;  // row j0+RPT vz
    float vxe[RPT] = {0, 0, 0, 0, 0};
    if (wx < 3 && lane == 63) {
      #pragma unroll
      for (int jj = 0; jj < RPT; ++jj) vxe[jj] = vxe_s[g][wx + 1][jj];
    }
    const float xi = wav_s[s];
    #pragma unroll
    for (int jj = 0; jj < RPT; ++jj) {
      float vxR = dpp_shl1(vxr[jj]);                 // vx[x+1] in-wave
      if (lane == 63) vxR = vxe[jj];                 // x==255 -> 0 ghost
      float vzn = (jj < RPT - 1) ? vz[jj + 1] : vzb_;
      float div = (vxR - vxr[jj]) + (vzn - vz[jj]);
      float rn = CA * rr[jj] - b2[jj] * div;
      rr[jj] = rn;
      float pn = pr[jj] - b3[jj] * div + DT * rn;
      if (zi0 + j0 + jj == sz && x == sx) pn += xi;  // source injection
      pr[jj] = pn;
    }
    pse[g][x] = pr[RPT - 1];
    if (wx < 3 && lane == 63) {
      #pragma unroll
      for (int jj = 0; jj < RPT; ++jj) pxe[g][wx][jj] = pr[jj];
    }
    if (owner) {                                     // stage receiver row
      #pragma unroll
      for (int jj = 0; jj < RPT; ++jj)
        if (j0 + jj == jrow) prow[x] = pr[jj];
    }
    __syncthreads();
    // probe reads complete before any thread reaches next A->B barrier -> safe
    if (owner && tid < NR)
      out[(size_t)(t0 + s) * NR * B + (size_t)tid * B + b] = prow[rx_s[tid]];
  }

  // ---- store owned rows (valid after exactly K steps) ----
  #pragma unroll
  for (int jj = 0; jj < RPT; ++jj) {
    int j = j0 + jj;
    if (j >= K && j < K + OROWS)
      Sout[base + (size_t)(zi0 + j) * NX + x] =
          make_float4(pr[jj], vxr[jj], vz[jj], rr[jj]);
  }
}

extern "C" void kernel_launch(void* const* d_in, const int* in_sizes, int n_in,
                              void* d_out, int out_size, void* d_ws, size_t ws_size,
                              hipStream_t stream) {
  const float* xw  = (const float*)d_in[0];
  const float* vp  = (const float*)d_in[1];
  const float* rho = (const float*)d_in[2];
  const float* Q   = (const float*)d_in[3];
  const int* src_z = (const int*)d_in[4];
  const int* src_x = (const int*)d_in[5];
  const int* rec_x = (const int*)d_in[6];
  const int* rec_z = (const int*)d_in[7];
  float* out = (float*)d_out;

  const size_t S = (size_t)B * NZ * NX;          // cells per state buffer
  float4* s0 = (float4*)d_ws;                    // state ping  [S] float4
  float4* s1 = s0 + S;                           // state pong  [S] float4
  float4* cf = s1 + S;                           // coefs       [NZ*NX] float4

  hipMemsetAsync(s0, 0, S * sizeof(float4), stream);   // zero initial state
  coef_kernel<<<(NZ * NX + 255) / 256, 256, 0, stream>>>(vp, rho, Q, cf);

  for (int l = 0; l < NL; ++l) {
    float4* in   = (l & 1) ? s1 : s0;
    float4* out4 = (l & 1) ? s0 : s1;
    step_fused<<<NBLK, 1024, 0, stream>>>(in, out4, cf, xw, src_z, src_x,
                                          rec_x, rec_z, out, l * K);
  }
}